// Round 2
// baseline (11227.377 us; speedup 1.0000x reference)
//
#include <hip/hip_runtime.h>
#include <hip/hip_bf16.h>

#define Bb 32
#define Tt 1024
#define Dd 768
#define Hh 768
#define NGRP 2       // independent batch groups (no cross-group sync)
#define BPG 96       // blocks per group
#define GB  16       // batches per group
#define CPB 8        // h-columns per block (96*8 = 768)
#define NTHREADS 192 // 3 waves = 3 N-tiles exactly
#define CNT_TGT (2 * BPG)  // 2 publishing waves per block

#define NWELE ((size_t)6 * Hh * Dd)   // W_in elements
#define NSELE ((size_t)5 * Hh * Hh)   // W_s elements
#define WS_NB    4096
#define WS_FLG   8192                 // 2 groups x Tt x 4B step counters
#define WS_HBOFF (WS_NB + WS_FLG)
#define HBSZ     (GB * Hh * 2)        // 24576 B per h buffer
#define WS_WGT   (WS_HBOFF + 4 * HBSZ)
#define WS_NEED  (WS_WGT + (NWELE + NSELE) * 2)

typedef short short8 __attribute__((ext_vector_type(8)));
typedef float f4 __attribute__((ext_vector_type(4)));

__device__ __forceinline__ float bf2f(ushort u) {
    unsigned x = (unsigned)u << 16;
    return __builtin_bit_cast(float, x);
}
__device__ __forceinline__ ushort f2bf(float f) {
    unsigned u = __builtin_bit_cast(unsigned, f);
    return (ushort)((u + 0x7fffu + ((u >> 16) & 1u)) >> 16);
}
__device__ __forceinline__ float sigm(float x) { return 1.0f / (1.0f + __expf(-x)); }
__device__ __forceinline__ float tanh_(float x) {
    float e = __expf(2.0f * x);
    return 1.0f - 2.0f / (e + 1.0f);
}

// nb[t] = number of active batches at step t (lengths sorted descending)
__global__ void prep_nb(const int* __restrict__ len, int* __restrict__ nbArr) {
    int t = blockIdx.x * 256 + threadIdx.x;
    if (t < Tt) {
        int c = 0;
#pragma unroll
        for (int b = 0; b < Bb; ++b) c += (len[b] > t) ? 1 : 0;
        nbArr[t] = c;
    }
}

// Convert (or copy) W_in and W_s into a packed bf16 image in ws.
__global__ void conv_w(const void* __restrict__ Win, const void* __restrict__ Ws,
                       const void* __restrict__ bs, ushort* __restrict__ wOut) {
    const bool isbf = (((const unsigned*)bs)[384] != 0u);
    size_t i = ((size_t)blockIdx.x * 256 + threadIdx.x) * 8;
    if (i >= NWELE + NSELE) return;
    const void* src = (i < NWELE) ? Win : Ws;
    size_t off = (i < NWELE) ? i : (i - NWELE);
    if (isbf) {
        *(uint4*)(wOut + i) = *(const uint4*)((const ushort*)src + off);
    } else {
        const f4* s = (const f4*)((const float*)src + off);
        f4 a = s[0], c = s[1];
        uint4 v;
        v.x = (unsigned)f2bf(a[0]) | ((unsigned)f2bf(a[1]) << 16);
        v.y = (unsigned)f2bf(a[2]) | ((unsigned)f2bf(a[3]) << 16);
        v.z = (unsigned)f2bf(c[0]) | ((unsigned)f2bf(c[1]) << 16);
        v.w = (unsigned)f2bf(c[2]) | ((unsigned)f2bf(c[3]) << 16);
        *(uint4*)(wOut + i) = v;
    }
}

// Persistent fused LSTM. Per step: register-prefetch x_{t+1} (overlaps GEMMs
// + poll), x-GEMM (W_in from L2), poll ONE per-step counter, ps-GEMM with A
// straight from the global h buffer, combine, publish + per-wave vmcnt(0) +
// counter add (no barrier on the release path), y buffered in LDS and flushed
// every 16 steps after the barrier. 2 barriers/step (was 3).
__global__ __launch_bounds__(NTHREADS, 1) void lstm_main(
    const void* __restrict__ inp, const void* __restrict__ bin,
    const void* __restrict__ bs, const int* __restrict__ len,
    void* __restrict__ y, const int* __restrict__ nbArr,
    unsigned* flags, ushort* hbAll, const ushort* __restrict__ wbf)
{
    __shared__ ushort wsL[48 * 776];     // W_s slice, rows 40..47 zero (74.5 KB)
    __shared__ ushort hA[2][16 * 776];   // double-buffered x K-operand (49.7 KB)
    __shared__ float accT[3][16][16];    // 3 N-tile results (3 KB)
    __shared__ float yBuf[16][128];      // 16-step y window (8 KB)

    const bool isbf = (((const unsigned*)bs)[384] != 0u);

    const int tid  = threadIdx.x;
    const int lane = tid & 63;
    const int wave = tid >> 6;           // 0..2 = N-tile
    const int g    = blockIdx.x & 1;     // group
    const int w    = blockIdx.x >> 1;    // block index within group, 0..95
    const int n0   = w * CPB;

    // --- W_s slice into LDS: zero all 48 rows, fill rows 0..39 ---
    for (int i = tid; i < 48 * 776 / 8; i += NTHREADS)
        *(uint4*)&wsL[i * 8] = uint4{0u, 0u, 0u, 0u};
    const ushort* wbfS = wbf + NWELE;
    __syncthreads();
    for (int i = tid; i < 40 * 96; i += NTHREADS) {
        int c = i / 96, ch = i - c * 96;
        *(uint4*)&wsL[c * 776 + ch * 8] =
            *(const uint4*)(wbfS + ((size_t)((c >> 3) * Hh + n0 + (c & 7))) * Hh + ch * 8);
    }

    // --- per-thread combine constants ---
    float B0 = 0, B1 = 0, B2 = 0, B3 = 0, B4 = 0, B5 = 0, cReg = 0.0f;
    int lenb = 0;
    if (tid < 128) {
        int j = tid & 7, n = n0 + j;
        if (isbf) {
            const ushort* bi = (const ushort*)bin; const ushort* bsp = (const ushort*)bs;
            B0 = bf2f(bi[0 * Hh + n]) + bf2f(bsp[0 * Hh + n]);
            B1 = bf2f(bi[1 * Hh + n]) + bf2f(bsp[1 * Hh + n]);
            B2 = bf2f(bi[2 * Hh + n]) + bf2f(bsp[2 * Hh + n]);
            B3 = bf2f(bi[3 * Hh + n]) + bf2f(bsp[3 * Hh + n]);
            B4 = bf2f(bi[4 * Hh + n]) + bf2f(bsp[4 * Hh + n]);
            B5 = bf2f(bi[5 * Hh + n]);
        } else {
            const float* bi = (const float*)bin; const float* bsp = (const float*)bs;
            B0 = bi[0 * Hh + n] + bsp[0 * Hh + n];
            B1 = bi[1 * Hh + n] + bsp[1 * Hh + n];
            B2 = bi[2 * Hh + n] + bsp[2 * Hh + n];
            B3 = bi[3 * Hh + n] + bsp[3 * Hh + n];
            B4 = bi[4 * Hh + n] + bsp[4 * Hh + n];
            B5 = bi[5 * Hh + n];
        }
        lenb = len[g * GB + (tid >> 3)];
    }

    // --- MFMA fragment addressing ---
    const int kq = (lane >> 4) << 3;
    const int aOff = (lane & 15) * 776 + kq;
    // A (h-half): DIRECT from global h buffer, u64 offset (4*kb+(lane>>4))*32+(lane&15)*2
    const int aoff = ((lane >> 4) * 32) + ((lane & 15) * 2);
    // B (x-half): W_in row for col cc = wave*16+(lane&15): gate=cc>>3, j=cc&7
    const int cc = wave * 16 + (lane & 15);
    const uint4* bPx = (const uint4*)(wbf + ((size_t)((cc >> 3) * Hh + n0 + (cc & 7))) * Dd + kq);
    // B (h-half): from LDS W_s slice, row cc (rows 40..47 are zeros)
    const ushort* wsP = &wsL[cc * 776 + kq];

    unsigned* cnt = flags + g * Tt;      // per-step publish counters
    ushort* hb[2] = {hbAll + (g * 2 + 0) * (HBSZ / 2),
                     hbAll + (g * 2 + 1) * (HBSZ / 2)};
    int p = 0;
    long gmax = (1L << 22);

    // --- prologue: stage x_0 into hA[0] ---
    if (isbf) {
        const ushort* xi = (const ushort*)inp;
        for (int i = tid; i < GB * 96; i += NTHREADS) {
            int row = i / 96, c8 = i - row * 96;
            *(uint4*)&hA[0][row * 776 + c8 * 8] =
                *((const uint4*)(xi + ((size_t)(g * GB + row) * Tt) * Dd) + c8);
        }
    } else {
        const float* xf = (const float*)inp;
        for (int i = tid; i < GB * 96; i += NTHREADS) {
            int row = i / 96, c8 = i - row * 96;
            const f4* s = (const f4*)(xf + ((size_t)(g * GB + row) * Tt) * Dd + c8 * 8);
            f4 a = s[0], c = s[1];
            uint4 v;
            v.x = (unsigned)f2bf(a[0]) | ((unsigned)f2bf(a[1]) << 16);
            v.y = (unsigned)f2bf(a[2]) | ((unsigned)f2bf(a[3]) << 16);
            v.z = (unsigned)f2bf(c[0]) | ((unsigned)f2bf(c[1]) << 16);
            v.w = (unsigned)f2bf(c[2]) | ((unsigned)f2bf(c[3]) << 16);
            *(uint4*)&hA[0][row * 776 + c8 * 8] = v;
        }
    }
    __syncthreads();

    int tDone = Tt;
    for (int t = 0; t < Tt; ++t) {
        int nbg = nbArr[t] - g * GB;
        nbg = nbg < 0 ? 0 : (nbg > GB ? GB : nbg);
        if (nbg == 0) { tDone = t; break; }

        // ---- issue x_{t+1} prefetch loads (in-flight across GEMMs + poll) ----
        uint4 pfA[8], pfB[8];
        const bool havePf = (t + 1 < Tt);
        if (havePf) {
            if (isbf) {
                const ushort* xi = (const ushort*)inp;
#pragma unroll
                for (int ii = 0; ii < 8; ++ii) {
                    int i = tid + ii * NTHREADS;
                    int row = i / 96, c8 = i - row * 96;
                    pfA[ii] = *((const uint4*)(xi + ((size_t)(g * GB + row) * Tt + (t + 1)) * Dd) + c8);
                }
            } else {
                const float* xf = (const float*)inp;
#pragma unroll
                for (int ii = 0; ii < 8; ++ii) {
                    int i = tid + ii * NTHREADS;
                    int row = i / 96, c8 = i - row * 96;
                    const uint4* s = (const uint4*)(xf + ((size_t)(g * GB + row) * Tt + (t + 1)) * Dd + c8 * 8);
                    pfA[ii] = s[0]; pfB[ii] = s[1];
                }
            }
        }

        // ---- x-GEMM (W_in from L2; overlaps flag propagation) ----
        const ushort* aP = &hA[t & 1][0] + aOff;
        f4 acc0 = {0, 0, 0, 0}, acc1 = {0, 0, 0, 0};
        f4 acc2 = {0, 0, 0, 0}, acc3 = {0, 0, 0, 0};
#pragma unroll
        for (int kb = 0; kb < 24; ++kb) {
            short8 a = __builtin_bit_cast(short8, *(const uint4*)(aP + kb * 32));
            short8 b = __builtin_bit_cast(short8, bPx[kb * 4]);
            switch (kb & 3) {
            case 0: acc0 = __builtin_amdgcn_mfma_f32_16x16x32_bf16(a, b, acc0, 0, 0, 0); break;
            case 1: acc1 = __builtin_amdgcn_mfma_f32_16x16x32_bf16(a, b, acc1, 0, 0, 0); break;
            case 2: acc2 = __builtin_amdgcn_mfma_f32_16x16x32_bf16(a, b, acc2, 0, 0, 0); break;
            default: acc3 = __builtin_amdgcn_mfma_f32_16x16x32_bf16(a, b, acc3, 0, 0, 0); break;
            }
        }

        // ---- group wait: poll ONE per-step counter (agent scope, backoff) ----
        if (t > 0) {
            long guard = 0;
            while (__hip_atomic_load(cnt + (t - 1), __ATOMIC_RELAXED,
                                     __HIP_MEMORY_SCOPE_AGENT) < (unsigned)CNT_TGT) {
                if (++guard > gmax) break;
                __builtin_amdgcn_s_sleep(1);
            }
        }
        __asm__ volatile("" ::: "memory");

        // ---- ps-GEMM: A-fragments straight from the global h buffer ----
        {
            const unsigned long long* aB = (const unsigned long long*)hb[p];
#pragma unroll
            for (int kb = 0; kb < 24; ++kb) {
                unsigned long long v0 = __hip_atomic_load(aB + kb * 128 + aoff,
                                                          __ATOMIC_RELAXED,
                                                          __HIP_MEMORY_SCOPE_AGENT);
                unsigned long long v1 = __hip_atomic_load(aB + kb * 128 + aoff + 1,
                                                          __ATOMIC_RELAXED,
                                                          __HIP_MEMORY_SCOPE_AGENT);
                short8 a;
                __builtin_memcpy(&a, &v0, 8);
                __builtin_memcpy((char*)&a + 8, &v1, 8);
                short8 b = __builtin_bit_cast(short8, *(const uint4*)(wsP + kb * 32));
                switch (kb & 3) {
                case 0: acc0 = __builtin_amdgcn_mfma_f32_16x16x32_bf16(a, b, acc0, 0, 0, 0); break;
                case 1: acc1 = __builtin_amdgcn_mfma_f32_16x16x32_bf16(a, b, acc1, 0, 0, 0); break;
                case 2: acc2 = __builtin_amdgcn_mfma_f32_16x16x32_bf16(a, b, acc2, 0, 0, 0); break;
                default: acc3 = __builtin_amdgcn_mfma_f32_16x16x32_bf16(a, b, acc3, 0, 0, 0); break;
                }
            }
        }
        {
            f4 s = (acc0 + acc1) + (acc2 + acc3);
            int r0 = (lane >> 4) * 4, col = lane & 15;
#pragma unroll
            for (int i = 0; i < 4; ++i) accT[wave][r0 + i][col] = s[i];
        }
        __syncthreads();   // (alpha) accT ready

        // ---- write prefetched x into hA[(t+1)&1] (all waves) ----
        if (havePf) {
            ushort* hN = &hA[(t + 1) & 1][0];
            if (isbf) {
#pragma unroll
                for (int ii = 0; ii < 8; ++ii) {
                    int i = tid + ii * NTHREADS;
                    int row = i / 96, c8 = i - row * 96;
                    *(uint4*)&hN[row * 776 + c8 * 8] = pfA[ii];
                }
            } else {
#pragma unroll
                for (int ii = 0; ii < 8; ++ii) {
                    int i = tid + ii * NTHREADS;
                    int row = i / 96, c8 = i - row * 96;
                    float f0 = __builtin_bit_cast(float, pfA[ii].x);
                    float f1 = __builtin_bit_cast(float, pfA[ii].y);
                    float f2 = __builtin_bit_cast(float, pfA[ii].z);
                    float f3 = __builtin_bit_cast(float, pfA[ii].w);
                    float f4_ = __builtin_bit_cast(float, pfB[ii].x);
                    float f5 = __builtin_bit_cast(float, pfB[ii].y);
                    float f6 = __builtin_bit_cast(float, pfB[ii].z);
                    float f7 = __builtin_bit_cast(float, pfB[ii].w);
                    uint4 v;
                    v.x = (unsigned)f2bf(f0) | ((unsigned)f2bf(f1) << 16);
                    v.y = (unsigned)f2bf(f2) | ((unsigned)f2bf(f3) << 16);
                    v.z = (unsigned)f2bf(f4_) | ((unsigned)f2bf(f5) << 16);
                    v.w = (unsigned)f2bf(f6) | ((unsigned)f2bf(f7) << 16);
                    *(uint4*)&hN[row * 776 + c8 * 8] = v;
                }
            }
        }

        // ---- combine + direct publish (shfl-gather) ----
        if (tid < 128) {
            int b = tid >> 3, j = tid & 7;
            float v0 = accT[(0 * 8 + j) >> 4][b][(0 * 8 + j) & 15];
            float v1 = accT[(1 * 8 + j) >> 4][b][(1 * 8 + j) & 15];
            float v2 = accT[(2 * 8 + j) >> 4][b][(2 * 8 + j) & 15];
            float v3 = accT[(3 * 8 + j) >> 4][b][(3 * 8 + j) & 15];
            float v4 = accT[(4 * 8 + j) >> 4][b][(4 * 8 + j) & 15];
            float v5 = accT[(5 * 8 + j) >> 4][b][(5 * 8 + j) & 15];
            float ii = sigm(v0 + B0);
            float ff = sigm(v1 + B1);
            float gg = tanh_(v2 + B2);
            float oo = sigm(v3 + B3);
            float hw = sigm(v4 + B4);
            float p5 = v5 + B5;
            float cn = ii * gg + ff * cReg;
            float outv = oo * tanh_(cn);
            outv = hw * outv + (1.0f - hw) * p5;
            bool act = t < lenb;
            if (act) cReg = cn;
            yBuf[t & 15][tid] = act ? outv : 0.0f;

            // gather 4 bf16 from the 4-lane subgroup; lanes j in {0,4} publish 8 B
            unsigned myv = (unsigned)f2bf(outv);
            int lane6 = tid & 63;
            int g0 = lane6 & ~3;
            unsigned a0 = (unsigned)__shfl((int)myv, g0 + 0);
            unsigned a1 = (unsigned)__shfl((int)myv, g0 + 1);
            unsigned a2 = (unsigned)__shfl((int)myv, g0 + 2);
            unsigned a3 = (unsigned)__shfl((int)myv, g0 + 3);
            if ((lane6 & 3) == 0 && act) {
                unsigned long long vv = (unsigned long long)(a0 & 0xffffu)
                    | ((unsigned long long)(a1 & 0xffffu) << 16)
                    | ((unsigned long long)(a2 & 0xffffu) << 32)
                    | ((unsigned long long)(a3 & 0xffffu) << 48);
                __hip_atomic_store(
                    (unsigned long long*)(hb[p ^ 1] + w * 128 + b * 8 + j),
                    vv, __ATOMIC_RELAXED, __HIP_MEMORY_SCOPE_AGENT);
            }
            // per-wave release: own-store drain + counter add (no block barrier)
            __asm__ volatile("s_waitcnt vmcnt(0)" ::: "memory");
            if ((tid & 63) == 0)
                __hip_atomic_fetch_add(cnt + t, 1u, __ATOMIC_RELAXED,
                                       __HIP_MEMORY_SCOPE_AGENT);
        }
        __syncthreads();   // (beta) hA[(t+1)&1] writes + yBuf window ordering

        // ---- y flush every 16 steps (after beta: acks drain a step later) ----
        if ((t & 15) == 15 && tid < 128) {
            int b = tid >> 3, j = tid & 7;
            int tBase = t - 15;
#pragma unroll
            for (int r = 0; r < 16; ++r) {
                size_t oi = ((size_t)(g * GB + b) * Tt + (tBase + r)) * Hh + n0 + j;
                float yv = yBuf[r][tid];
                if (isbf) ((ushort*)y)[oi] = f2bf(yv);
                else      ((float*)y)[oi]  = yv;
            }
        }
        p ^= 1;
    }

    // ---- epilogue: partial window flush + tail zeros ----
    if (tid < 128) {
        int b = tid >> 3, j = tid & 7;
        int tBase = tDone & ~15;
        for (int r = 0; r < (tDone & 15); ++r) {
            size_t oi = ((size_t)(g * GB + b) * Tt + (tBase + r)) * Hh + n0 + j;
            float yv = yBuf[r][tid];
            if (isbf) ((ushort*)y)[oi] = f2bf(yv);
            else      ((float*)y)[oi]  = yv;
        }
        for (int t = tDone; t < Tt; ++t) {
            size_t oi = ((size_t)(g * GB + b) * Tt + t) * Hh + n0 + j;
            if (isbf) ((ushort*)y)[oi] = 0; else ((float*)y)[oi] = 0.0f;
        }
    }
}

extern "C" void kernel_launch(void* const* d_in, const int* in_sizes, int n_in,
                              void* d_out, int out_size, void* d_ws, size_t ws_size,
                              hipStream_t stream) {
    const void* inp = d_in[0];
    const void* Win = d_in[1];
    const void* bin = d_in[2];
    const void* Ws  = d_in[3];
    const void* bs  = d_in[4];
    const int*  len = (const int*)d_in[5];

    if (ws_size < WS_NEED) return;  // evidence: >=26.6 MB granted; need ~13.1 MB

    char* ws = (char*)d_ws;
    int* nbArr      = (int*)ws;
    unsigned* flags = (unsigned*)(ws + WS_NB);
    ushort* hbAll   = (ushort*)(ws + WS_HBOFF);
    ushort* wbf     = (ushort*)(ws + WS_WGT);

    hipMemsetAsync(d_ws, 0, WS_WGT, stream);   // nbArr/counters/h buffers = 0
    prep_nb<<<4, 256, 0, stream>>>(len, nbArr);
    conv_w<<<3168, 256, 0, stream>>>(Win, Ws, bs, wbf);
    lstm_main<<<NGRP * BPG, NTHREADS, 0, stream>>>(inp, bin, bs, len, d_out,
                                                   nbArr, flags, hbAll, wbf);
}

// Round 3
// 9613.079 us; speedup vs baseline: 1.1679x; 1.1679x over previous
//
#include <hip/hip_runtime.h>
#include <hip/hip_bf16.h>

#define Bb 32
#define Tt 1024
#define Dd 768
#define Hh 768
#define NGRP 2       // independent batch groups (no cross-group sync)
#define BPG 96       // blocks per group
#define GB  16       // batches per group
#define CPB 8        // h-columns per block (96*8 = 768)
#define NTHREADS 192 // 3 waves = 3 N-tiles exactly

#define NWELE ((size_t)6 * Hh * Dd)   // W_in elements
#define NSELE ((size_t)5 * Hh * Hh)   // W_s elements
#define WS_NB    4096
#define WS_FLG   8192                 // 2 groups x 2 replicas x 256 slots
#define WS_HBOFF (WS_NB + WS_FLG)
#define HBSZ     (GB * Hh * 2)        // 24576 B per h buffer
#define WS_WGT   (WS_HBOFF + 4 * HBSZ)
#define WS_NEED  (WS_WGT + (NWELE + NSELE) * 2)

typedef short short8 __attribute__((ext_vector_type(8)));
typedef float f4 __attribute__((ext_vector_type(4)));

__device__ __forceinline__ float bf2f(ushort u) {
    unsigned x = (unsigned)u << 16;
    return __builtin_bit_cast(float, x);
}
__device__ __forceinline__ ushort f2bf(float f) {
    unsigned u = __builtin_bit_cast(unsigned, f);
    return (ushort)((u + 0x7fffu + ((u >> 16) & 1u)) >> 16);
}
__device__ __forceinline__ float sigm(float x) { return 1.0f / (1.0f + __expf(-x)); }
__device__ __forceinline__ float tanh_(float x) {
    float e = __expf(2.0f * x);
    return 1.0f - 2.0f / (e + 1.0f);
}

// nb[t] = number of active batches at step t (lengths sorted descending)
__global__ void prep_nb(const int* __restrict__ len, int* __restrict__ nbArr) {
    int t = blockIdx.x * 256 + threadIdx.x;
    if (t < Tt) {
        int c = 0;
#pragma unroll
        for (int b = 0; b < Bb; ++b) c += (len[b] > t) ? 1 : 0;
        nbArr[t] = c;
    }
}

// Convert (or copy) W_in and W_s into a packed bf16 image in ws.
__global__ void conv_w(const void* __restrict__ Win, const void* __restrict__ Ws,
                       const void* __restrict__ bs, ushort* __restrict__ wOut) {
    const bool isbf = (((const unsigned*)bs)[384] != 0u);
    size_t i = ((size_t)blockIdx.x * 256 + threadIdx.x) * 8;
    if (i >= NWELE + NSELE) return;
    const void* src = (i < NWELE) ? Win : Ws;
    size_t off = (i < NWELE) ? i : (i - NWELE);
    if (isbf) {
        *(uint4*)(wOut + i) = *(const uint4*)((const ushort*)src + off);
    } else {
        const f4* s = (const f4*)((const float*)src + off);
        f4 a = s[0], c = s[1];
        uint4 v;
        v.x = (unsigned)f2bf(a[0]) | ((unsigned)f2bf(a[1]) << 16);
        v.y = (unsigned)f2bf(a[2]) | ((unsigned)f2bf(a[3]) << 16);
        v.z = (unsigned)f2bf(c[0]) | ((unsigned)f2bf(c[1]) << 16);
        v.w = (unsigned)f2bf(c[2]) | ((unsigned)f2bf(c[3]) << 16);
        *(uint4*)(wOut + i) = v;
    }
}

// Persistent fused LSTM, 2 groups x 96 blocks x 16 batches, CPB=8 h-cols.
// Sync redesign vs R1: 192 per-WAVE flags (2 replicas) -> wave-autonomous
// release (own vmcnt drain + flag store, no block barrier on release path);
// only wave 0 polls the fabric (6x less flag-line traffic), waves 1-2 released
// via LDS spin. 2 barriers/step.
__global__ __launch_bounds__(NTHREADS, 1) void lstm_main(
    const void* __restrict__ inp, const void* __restrict__ bin,
    const void* __restrict__ bs, const int* __restrict__ len,
    void* __restrict__ y, const int* __restrict__ nbArr,
    unsigned* flags, ushort* hbAll, const ushort* __restrict__ wbf)
{
    __shared__ ushort wsL[48 * 776];     // W_s slice, rows 40..47 zero (74.5 KB)
    __shared__ ushort hA[GB * 776];      // staged x K-operand (24.8 KB)
    __shared__ float accT[3][16][16];    // 3 N-tile results (3 KB)
    __shared__ int step_rdy;             // LDS relay for waves 1-2

    const bool isbf = (((const unsigned*)bs)[384] != 0u);

    const int tid  = threadIdx.x;
    const int lane = tid & 63;
    const int wave = tid >> 6;           // 0..2 = N-tile
    const int g    = blockIdx.x & 1;     // group
    const int w    = blockIdx.x >> 1;    // block index within group, 0..95
    const int n0   = w * CPB;

    if (tid == 0) step_rdy = 0;

    // --- W_s slice into LDS: zero all 48 rows, fill rows 0..39 ---
    for (int i = tid; i < 48 * 776 / 8; i += NTHREADS)
        *(uint4*)&wsL[i * 8] = uint4{0u, 0u, 0u, 0u};
    const ushort* wbfS = wbf + NWELE;
    __syncthreads();
    for (int i = tid; i < 40 * 96; i += NTHREADS) {
        int c = i / 96, ch = i - c * 96;
        *(uint4*)&wsL[c * 776 + ch * 8] =
            *(const uint4*)(wbfS + ((size_t)((c >> 3) * Hh + n0 + (c & 7))) * Hh + ch * 8);
    }

    // --- per-thread combine constants ---
    float B0 = 0, B1 = 0, B2 = 0, B3 = 0, B4 = 0, B5 = 0, cReg = 0.0f;
    int lenb = 0;
    if (tid < 128) {
        int j = tid & 7, n = n0 + j;
        if (isbf) {
            const ushort* bi = (const ushort*)bin; const ushort* bsp = (const ushort*)bs;
            B0 = bf2f(bi[0 * Hh + n]) + bf2f(bsp[0 * Hh + n]);
            B1 = bf2f(bi[1 * Hh + n]) + bf2f(bsp[1 * Hh + n]);
            B2 = bf2f(bi[2 * Hh + n]) + bf2f(bsp[2 * Hh + n]);
            B3 = bf2f(bi[3 * Hh + n]) + bf2f(bsp[3 * Hh + n]);
            B4 = bf2f(bi[4 * Hh + n]) + bf2f(bsp[4 * Hh + n]);
            B5 = bf2f(bi[5 * Hh + n]);
        } else {
            const float* bi = (const float*)bin; const float* bsp = (const float*)bs;
            B0 = bi[0 * Hh + n] + bsp[0 * Hh + n];
            B1 = bi[1 * Hh + n] + bsp[1 * Hh + n];
            B2 = bi[2 * Hh + n] + bsp[2 * Hh + n];
            B3 = bi[3 * Hh + n] + bsp[3 * Hh + n];
            B4 = bi[4 * Hh + n] + bsp[4 * Hh + n];
            B5 = bi[5 * Hh + n];
        }
        lenb = len[g * GB + (tid >> 3)];
    }

    // --- MFMA fragment addressing ---
    const int kq = (lane >> 4) << 3;
    const ushort* aP = &hA[(lane & 15) * 776 + kq];
    // A (h-half): DIRECT from global h buffer, u64 offset (4*kb+(lane>>4))*32+(lane&15)*2
    const int aoff = ((lane >> 4) * 32) + ((lane & 15) * 2);
    // B (x-half): W_in row for col cc = wave*16+(lane&15): gate=cc>>3, j=cc&7
    const int cc = wave * 16 + (lane & 15);
    const uint4* bPx = (const uint4*)(wbf + ((size_t)((cc >> 3) * Hh + n0 + (cc & 7))) * Dd + kq);
    // B (h-half): from LDS W_s slice, row cc (rows 40..47 are zeros)
    const ushort* wsP = &wsL[cc * 776 + kq];

    unsigned* wflg = flags + g * 512;    // 192 wave-flags x 2 replicas
    const int repo = (w & 1) ? 256 : 0;  // which replica this block polls
    ushort* hb[2] = {hbAll + (g * 2 + 0) * (HBSZ / 2),
                     hbAll + (g * 2 + 1) * (HBSZ / 2)};
    int p = 0;
    long gmax = (1L << 22);
    __syncthreads();

    int tDone = Tt;
    for (int t = 0; t < Tt; ++t) {
        int nbg = nbArr[t] - g * GB;
        nbg = nbg < 0 ? 0 : (nbg > GB ? GB : nbg);
        if (nbg == 0) { tDone = t; break; }

        // ---- stage x_t (16 rows, convert to bf16) ----
        if (isbf) {
            const ushort* xi = (const ushort*)inp;
            for (int i = tid; i < GB * 96; i += NTHREADS) {
                int row = i / 96, c8 = i - row * 96;
                *(uint4*)&hA[row * 776 + c8 * 8] =
                    *((const uint4*)(xi + ((size_t)(g * GB + row) * Tt + t) * Dd) + c8);
            }
        } else {
            const float* xf = (const float*)inp;
            for (int i = tid; i < GB * 96; i += NTHREADS) {
                int row = i / 96, c8 = i - row * 96;
                const f4* s = (const f4*)(xf + ((size_t)(g * GB + row) * Tt + t) * Dd + c8 * 8);
                f4 a = s[0], c = s[1];
                uint4 v;
                v.x = (unsigned)f2bf(a[0]) | ((unsigned)f2bf(a[1]) << 16);
                v.y = (unsigned)f2bf(a[2]) | ((unsigned)f2bf(a[3]) << 16);
                v.z = (unsigned)f2bf(c[0]) | ((unsigned)f2bf(c[1]) << 16);
                v.w = (unsigned)f2bf(c[2]) | ((unsigned)f2bf(c[3]) << 16);
                *(uint4*)&hA[row * 776 + c8 * 8] = v;
            }
        }
        __syncthreads();   // (1) hA ready; also drains prev-step y stores

        // ---- x-GEMM (W_in from L2; overlaps flag propagation) ----
        f4 acc0 = {0, 0, 0, 0}, acc1 = {0, 0, 0, 0};
        f4 acc2 = {0, 0, 0, 0}, acc3 = {0, 0, 0, 0};
#pragma unroll
        for (int kb = 0; kb < 24; ++kb) {
            short8 a = __builtin_bit_cast(short8, *(const uint4*)(aP + kb * 32));
            short8 b = __builtin_bit_cast(short8, bPx[kb * 4]);
            switch (kb & 3) {
            case 0: acc0 = __builtin_amdgcn_mfma_f32_16x16x32_bf16(a, b, acc0, 0, 0, 0); break;
            case 1: acc1 = __builtin_amdgcn_mfma_f32_16x16x32_bf16(a, b, acc1, 0, 0, 0); break;
            case 2: acc2 = __builtin_amdgcn_mfma_f32_16x16x32_bf16(a, b, acc2, 0, 0, 0); break;
            default: acc3 = __builtin_amdgcn_mfma_f32_16x16x32_bf16(a, b, acc3, 0, 0, 0); break;
            }
        }

        // ---- group wait: wave 0 polls fabric (192 flags, own replica),
        //      waves 1-2 spin on LDS relay ----
        if (t > 0) {
            if (wave == 0) {
                const unsigned target = (unsigned)t;
                long guard = 0;
                for (;;) {
                    unsigned f0 = __hip_atomic_load(wflg + repo + lane,
                                                    __ATOMIC_RELAXED, __HIP_MEMORY_SCOPE_AGENT);
                    unsigned f1 = __hip_atomic_load(wflg + repo + 64 + lane,
                                                    __ATOMIC_RELAXED, __HIP_MEMORY_SCOPE_AGENT);
                    unsigned f2 = __hip_atomic_load(wflg + repo + 128 + lane,
                                                    __ATOMIC_RELAXED, __HIP_MEMORY_SCOPE_AGENT);
                    bool ok = (f0 >= target) && (f1 >= target) && (f2 >= target);
                    if (__all(ok)) break;
                    if (++guard > gmax) break;
                    __builtin_amdgcn_s_sleep(2);
                }
                if (lane == 0)
                    __hip_atomic_store(&step_rdy, t, __ATOMIC_RELAXED,
                                       __HIP_MEMORY_SCOPE_WORKGROUP);
            } else {
                long guard = 0;
                while (__hip_atomic_load(&step_rdy, __ATOMIC_RELAXED,
                                         __HIP_MEMORY_SCOPE_WORKGROUP) < t) {
                    if (++guard > gmax) break;
                    __builtin_amdgcn_s_sleep(1);
                }
            }
        }
        __asm__ volatile("" ::: "memory");

        // ---- ps-GEMM: A-fragments straight from the global h buffer ----
        {
            const unsigned long long* aB = (const unsigned long long*)hb[p];
#pragma unroll
            for (int kb = 0; kb < 24; ++kb) {
                unsigned long long v0 = __hip_atomic_load(aB + kb * 128 + aoff,
                                                          __ATOMIC_RELAXED,
                                                          __HIP_MEMORY_SCOPE_AGENT);
                unsigned long long v1 = __hip_atomic_load(aB + kb * 128 + aoff + 1,
                                                          __ATOMIC_RELAXED,
                                                          __HIP_MEMORY_SCOPE_AGENT);
                short8 a;
                __builtin_memcpy(&a, &v0, 8);
                __builtin_memcpy((char*)&a + 8, &v1, 8);
                short8 b = __builtin_bit_cast(short8, *(const uint4*)(wsP + kb * 32));
                switch (kb & 3) {
                case 0: acc0 = __builtin_amdgcn_mfma_f32_16x16x32_bf16(a, b, acc0, 0, 0, 0); break;
                case 1: acc1 = __builtin_amdgcn_mfma_f32_16x16x32_bf16(a, b, acc1, 0, 0, 0); break;
                case 2: acc2 = __builtin_amdgcn_mfma_f32_16x16x32_bf16(a, b, acc2, 0, 0, 0); break;
                default: acc3 = __builtin_amdgcn_mfma_f32_16x16x32_bf16(a, b, acc3, 0, 0, 0); break;
                }
            }
        }
        {
            f4 s = (acc0 + acc1) + (acc2 + acc3);
            int r0 = (lane >> 4) * 4, col = lane & 15;
#pragma unroll
            for (int i = 0; i < 4; ++i) accT[wave][r0 + i][col] = s[i];
        }
        __syncthreads();   // (2) accT ready

        // ---- combine + publish + wave-autonomous release (waves 0,1) ----
        if (tid < 128) {
            int b = tid >> 3, j = tid & 7;
            float v0 = accT[(0 * 8 + j) >> 4][b][(0 * 8 + j) & 15];
            float v1 = accT[(1 * 8 + j) >> 4][b][(1 * 8 + j) & 15];
            float v2 = accT[(2 * 8 + j) >> 4][b][(2 * 8 + j) & 15];
            float v3 = accT[(3 * 8 + j) >> 4][b][(3 * 8 + j) & 15];
            float v4 = accT[(4 * 8 + j) >> 4][b][(4 * 8 + j) & 15];
            float v5 = accT[(5 * 8 + j) >> 4][b][(5 * 8 + j) & 15];
            float ii = sigm(v0 + B0);
            float ff = sigm(v1 + B1);
            float gg = tanh_(v2 + B2);
            float oo = sigm(v3 + B3);
            float hw = sigm(v4 + B4);
            float p5 = v5 + B5;
            float cn = ii * gg + ff * cReg;
            float outv = oo * tanh_(cn);
            outv = hw * outv + (1.0f - hw) * p5;
            bool act = t < lenb;
            if (act) cReg = cn;

            // gather 4 bf16 from the 4-lane subgroup; lanes j in {0,4} publish 8 B
            unsigned myv = (unsigned)f2bf(outv);
            int lane6 = tid & 63;
            int g0 = lane6 & ~3;
            unsigned a0 = (unsigned)__shfl((int)myv, g0 + 0);
            unsigned a1 = (unsigned)__shfl((int)myv, g0 + 1);
            unsigned a2 = (unsigned)__shfl((int)myv, g0 + 2);
            unsigned a3 = (unsigned)__shfl((int)myv, g0 + 3);
            if ((lane6 & 3) == 0 && act) {
                unsigned long long vv = (unsigned long long)(a0 & 0xffffu)
                    | ((unsigned long long)(a1 & 0xffffu) << 16)
                    | ((unsigned long long)(a2 & 0xffffu) << 32)
                    | ((unsigned long long)(a3 & 0xffffu) << 48);
                __hip_atomic_store(
                    (unsigned long long*)(hb[p ^ 1] + w * 128 + b * 8 + j),
                    vv, __ATOMIC_RELAXED, __HIP_MEMORY_SCOPE_AGENT);
            }
            // wave-autonomous release: drain own stores, then set own wave-flag
            __asm__ volatile("s_waitcnt vmcnt(0)" ::: "memory");
            if (lane6 == 0) {
                int idx = w * 2 + (tid >> 6);
                __hip_atomic_store(wflg + idx, (unsigned)(t + 1),
                                   __ATOMIC_RELAXED, __HIP_MEMORY_SCOPE_AGENT);
                __hip_atomic_store(wflg + 256 + idx, (unsigned)(t + 1),
                                   __ATOMIC_RELAXED, __HIP_MEMORY_SCOPE_AGENT);
            }

            // ---- y write AFTER the flag (ack off the critical path) ----
            size_t oi = ((size_t)(g * GB + b) * Tt + t) * Hh + n0 + j;
            if (isbf) ((ushort*)y)[oi] = act ? f2bf(outv) : (ushort)0;
            else      ((float*)y)[oi]  = act ? outv : 0.0f;
        }
        p ^= 1;
    }

    // ---- tail: group finished -> zero its remaining y cells ----
    if (tid < 128) {
        int b = tid >> 3, j = tid & 7;
        for (int t = tDone; t < Tt; ++t) {
            size_t oi = ((size_t)(g * GB + b) * Tt + t) * Hh + n0 + j;
            if (isbf) ((ushort*)y)[oi] = 0; else ((float*)y)[oi] = 0.0f;
        }
    }
}

extern "C" void kernel_launch(void* const* d_in, const int* in_sizes, int n_in,
                              void* d_out, int out_size, void* d_ws, size_t ws_size,
                              hipStream_t stream) {
    const void* inp = d_in[0];
    const void* Win = d_in[1];
    const void* bin = d_in[2];
    const void* Ws  = d_in[3];
    const void* bs  = d_in[4];
    const int*  len = (const int*)d_in[5];

    if (ws_size < WS_NEED) return;  // evidence: >=26.6 MB granted; need ~13.1 MB

    char* ws = (char*)d_ws;
    int* nbArr      = (int*)ws;
    unsigned* flags = (unsigned*)(ws + WS_NB);
    ushort* hbAll   = (ushort*)(ws + WS_HBOFF);
    ushort* wbf     = (ushort*)(ws + WS_WGT);

    hipMemsetAsync(d_ws, 0, WS_WGT, stream);   // nbArr/flags/h buffers = 0
    prep_nb<<<4, 256, 0, stream>>>(len, nbArr);
    conv_w<<<3168, 256, 0, stream>>>(Win, Ws, bs, wbf);
    lstm_main<<<NGRP * BPG, NTHREADS, 0, stream>>>(inp, bin, bs, len, d_out,
                                                   nbArr, flags, hbAll, wbf);
}

// Round 4
// 8659.578 us; speedup vs baseline: 1.2965x; 1.1101x over previous
//
#include <hip/hip_runtime.h>
#include <hip/hip_bf16.h>

#define Bb 32
#define Tt 1024
#define Dd 768
#define Hh 768
#define NGRP 2       // independent batch groups (no cross-group sync)
#define BPG 96       // blocks per group
#define GB  16       // batches per group
#define CPB 8        // h-columns per block (96*8 = 768)
#define NTHREADS 192 // 3 waves = 3 N-tiles exactly

#define NWELE ((size_t)6 * Hh * Dd)   // W_in elements
#define NSELE ((size_t)5 * Hh * Hh)   // W_s elements
#define WS_NB    4096
#define WS_FLG   8192                 // 2 groups x 256 wave-flag slots
#define WS_HBOFF (WS_NB + WS_FLG)
#define HBSZ     (GB * Hh * 2)        // 24576 B per h buffer
#define WS_WGT   (WS_HBOFF + 4 * HBSZ)
#define WS_NEED  (WS_WGT + (NWELE + NSELE) * 2)

typedef short short8 __attribute__((ext_vector_type(8)));
typedef float f4 __attribute__((ext_vector_type(4)));

__device__ __forceinline__ float bf2f(ushort u) {
    unsigned x = (unsigned)u << 16;
    return __builtin_bit_cast(float, x);
}
__device__ __forceinline__ ushort f2bf(float f) {
    unsigned u = __builtin_bit_cast(unsigned, f);
    return (ushort)((u + 0x7fffu + ((u >> 16) & 1u)) >> 16);
}
__device__ __forceinline__ float sigm(float x) { return 1.0f / (1.0f + __expf(-x)); }
__device__ __forceinline__ float tanh_(float x) {
    float e = __expf(2.0f * x);
    return 1.0f - 2.0f / (e + 1.0f);
}

// nb[t] = number of active batches at step t (lengths sorted descending)
__global__ void prep_nb(const int* __restrict__ len, int* __restrict__ nbArr) {
    int t = blockIdx.x * 256 + threadIdx.x;
    if (t < Tt) {
        int c = 0;
#pragma unroll
        for (int b = 0; b < Bb; ++b) c += (len[b] > t) ? 1 : 0;
        nbArr[t] = c;
    }
}

// Convert (or copy) W_in and W_s into a packed bf16 image in ws.
__global__ void conv_w(const void* __restrict__ Win, const void* __restrict__ Ws,
                       const void* __restrict__ bs, ushort* __restrict__ wOut) {
    const bool isbf = (((const unsigned*)bs)[384] != 0u);
    size_t i = ((size_t)blockIdx.x * 256 + threadIdx.x) * 8;
    if (i >= NWELE + NSELE) return;
    const void* src = (i < NWELE) ? Win : Ws;
    size_t off = (i < NWELE) ? i : (i - NWELE);
    if (isbf) {
        *(uint4*)(wOut + i) = *(const uint4*)((const ushort*)src + off);
    } else {
        const f4* s = (const f4*)((const float*)src + off);
        f4 a = s[0], c = s[1];
        uint4 v;
        v.x = (unsigned)f2bf(a[0]) | ((unsigned)f2bf(a[1]) << 16);
        v.y = (unsigned)f2bf(a[2]) | ((unsigned)f2bf(a[3]) << 16);
        v.z = (unsigned)f2bf(c[0]) | ((unsigned)f2bf(c[1]) << 16);
        v.w = (unsigned)f2bf(c[2]) | ((unsigned)f2bf(c[3]) << 16);
        *(uint4*)(wOut + i) = v;
    }
}

// Persistent fused LSTM. R4 restructure: the flag-to-flag chain carries ONLY
// h-dependent work (poll -> ps-GEMM -> b2 -> combine -> publish+drain -> flag).
// x is register-prefetched one step ahead and written to LDS after the flag;
// x-GEMM for step t+1 runs after publishing step t (acc carries across the
// back-edge); y is stored as 16B float4 at iter end so its RMW ack drains a
// full chain later. Per-wave flags; all waves self-release via poll.
__global__ __launch_bounds__(NTHREADS, 1) void lstm_main(
    const void* __restrict__ inp, const void* __restrict__ bin,
    const void* __restrict__ bs, const int* __restrict__ len,
    void* __restrict__ y, const int* __restrict__ nbArr,
    unsigned* flags, ushort* hbAll, const ushort* __restrict__ wbf)
{
    __shared__ ushort wsL[48 * 776];     // W_s slice, rows 40..47 zero (74.5 KB)
    __shared__ ushort hA[GB * 776];      // staged x K-operand (24.8 KB, single buf)
    __shared__ float accT[3][16][16];    // 3 N-tile results (3 KB)

    const bool isbf = (((const unsigned*)bs)[384] != 0u);

    const int tid  = threadIdx.x;
    const int lane = tid & 63;
    const int wave = tid >> 6;           // 0..2 = N-tile
    const int g    = blockIdx.x & 1;     // group
    const int w    = blockIdx.x >> 1;    // block index within group, 0..95
    const int n0   = w * CPB;

    // --- W_s slice into LDS: zero all 48 rows, fill rows 0..39 ---
    for (int i = tid; i < 48 * 776 / 8; i += NTHREADS)
        *(uint4*)&wsL[i * 8] = uint4{0u, 0u, 0u, 0u};
    const ushort* wbfS = wbf + NWELE;
    __syncthreads();
    for (int i = tid; i < 40 * 96; i += NTHREADS) {
        int c = i / 96, ch = i - c * 96;
        *(uint4*)&wsL[c * 776 + ch * 8] =
            *(const uint4*)(wbfS + ((size_t)((c >> 3) * Hh + n0 + (c & 7))) * Hh + ch * 8);
    }

    // --- per-thread combine constants ---
    float B0 = 0, B1 = 0, B2 = 0, B3 = 0, B4 = 0, B5 = 0, cReg = 0.0f;
    int lenb = 0;
    if (tid < 128) {
        int j = tid & 7, n = n0 + j;
        if (isbf) {
            const ushort* bi = (const ushort*)bin; const ushort* bsp = (const ushort*)bs;
            B0 = bf2f(bi[0 * Hh + n]) + bf2f(bsp[0 * Hh + n]);
            B1 = bf2f(bi[1 * Hh + n]) + bf2f(bsp[1 * Hh + n]);
            B2 = bf2f(bi[2 * Hh + n]) + bf2f(bsp[2 * Hh + n]);
            B3 = bf2f(bi[3 * Hh + n]) + bf2f(bsp[3 * Hh + n]);
            B4 = bf2f(bi[4 * Hh + n]) + bf2f(bsp[4 * Hh + n]);
            B5 = bf2f(bi[5 * Hh + n]);
        } else {
            const float* bi = (const float*)bin; const float* bsp = (const float*)bs;
            B0 = bi[0 * Hh + n] + bsp[0 * Hh + n];
            B1 = bi[1 * Hh + n] + bsp[1 * Hh + n];
            B2 = bi[2 * Hh + n] + bsp[2 * Hh + n];
            B3 = bi[3 * Hh + n] + bsp[3 * Hh + n];
            B4 = bi[4 * Hh + n] + bsp[4 * Hh + n];
            B5 = bi[5 * Hh + n];
        }
        lenb = len[g * GB + (tid >> 3)];
    }

    // --- MFMA fragment addressing ---
    const int kq = (lane >> 4) << 3;
    const ushort* aP = &hA[(lane & 15) * 776 + kq];
    // A (h-half): DIRECT from global h buffer, u64 offset (4*kb+(lane>>4))*32+(lane&15)*2
    const int aoff = ((lane >> 4) * 32) + ((lane & 15) * 2);
    // B (x-half): W_in row for col cc = wave*16+(lane&15): gate=cc>>3, j=cc&7
    const int cc = wave * 16 + (lane & 15);
    const uint4* bPx = (const uint4*)(wbf + ((size_t)((cc >> 3) * Hh + n0 + (cc & 7))) * Dd + kq);
    // B (h-half): from LDS W_s slice, row cc (rows 40..47 are zeros)
    const ushort* wsP = &wsL[cc * 776 + kq];

    unsigned* wflg = flags + g * 256;    // 192 wave-flags (2 per block)
    ushort* hb[2] = {hbAll + (g * 2 + 0) * (HBSZ / 2),
                     hbAll + (g * 2 + 1) * (HBSZ / 2)};
    long gmax = (1L << 22);

    // --- x prefetch machinery (registers hold x_{t+1} raw) ---
    uint4 pfA[8], pfB[8];
    auto pfIssue = [&](int tn) {
        if (isbf) {
            const ushort* xi = (const ushort*)inp;
#pragma unroll
            for (int ii = 0; ii < 8; ++ii) {
                int i = tid + ii * NTHREADS;
                int row = i / 96, c8 = i - row * 96;
                pfA[ii] = *((const uint4*)(xi + ((size_t)(g * GB + row) * Tt + tn) * Dd) + c8);
            }
        } else {
            const float* xf = (const float*)inp;
#pragma unroll
            for (int ii = 0; ii < 8; ++ii) {
                int i = tid + ii * NTHREADS;
                int row = i / 96, c8 = i - row * 96;
                const uint4* s = (const uint4*)(xf + ((size_t)(g * GB + row) * Tt + tn) * Dd + c8 * 8);
                pfA[ii] = s[0]; pfB[ii] = s[1];
            }
        }
    };
    auto pfWrite = [&]() {
        if (isbf) {
#pragma unroll
            for (int ii = 0; ii < 8; ++ii) {
                int i = tid + ii * NTHREADS;
                int row = i / 96, c8 = i - row * 96;
                *(uint4*)&hA[row * 776 + c8 * 8] = pfA[ii];
            }
        } else {
#pragma unroll
            for (int ii = 0; ii < 8; ++ii) {
                int i = tid + ii * NTHREADS;
                int row = i / 96, c8 = i - row * 96;
                float f0 = __builtin_bit_cast(float, pfA[ii].x);
                float f1 = __builtin_bit_cast(float, pfA[ii].y);
                float f2 = __builtin_bit_cast(float, pfA[ii].z);
                float f3 = __builtin_bit_cast(float, pfA[ii].w);
                float f4_ = __builtin_bit_cast(float, pfB[ii].x);
                float f5 = __builtin_bit_cast(float, pfB[ii].y);
                float f6 = __builtin_bit_cast(float, pfB[ii].z);
                float f7 = __builtin_bit_cast(float, pfB[ii].w);
                uint4 v;
                v.x = (unsigned)f2bf(f0) | ((unsigned)f2bf(f1) << 16);
                v.y = (unsigned)f2bf(f2) | ((unsigned)f2bf(f3) << 16);
                v.z = (unsigned)f2bf(f4_) | ((unsigned)f2bf(f5) << 16);
                v.w = (unsigned)f2bf(f6) | ((unsigned)f2bf(f7) << 16);
                *(uint4*)&hA[row * 776 + c8 * 8] = v;
            }
        }
    };

    // --- prologue: stage x_0, x-GEMM(0), prefetch x_1 ---
    pfIssue(0);
    pfWrite();
    __syncthreads();                     // hA(x_0) + wsL ready

    f4 acc0 = {0, 0, 0, 0}, acc1 = {0, 0, 0, 0};
    f4 acc2 = {0, 0, 0, 0}, acc3 = {0, 0, 0, 0};
#pragma unroll
    for (int kb = 0; kb < 24; ++kb) {
        short8 a = __builtin_bit_cast(short8, *(const uint4*)(aP + kb * 32));
        short8 b = __builtin_bit_cast(short8, bPx[kb * 4]);
        switch (kb & 3) {
        case 0: acc0 = __builtin_amdgcn_mfma_f32_16x16x32_bf16(a, b, acc0, 0, 0, 0); break;
        case 1: acc1 = __builtin_amdgcn_mfma_f32_16x16x32_bf16(a, b, acc1, 0, 0, 0); break;
        case 2: acc2 = __builtin_amdgcn_mfma_f32_16x16x32_bf16(a, b, acc2, 0, 0, 0); break;
        default: acc3 = __builtin_amdgcn_mfma_f32_16x16x32_bf16(a, b, acc3, 0, 0, 0); break;
        }
    }
    pfIssue(1);
    __builtin_amdgcn_sched_barrier(0);

    int tDone = Tt;
    for (int t = 0; t < Tt; ++t) {
        int nbg = nbArr[t] - g * GB;
        nbg = nbg < 0 ? 0 : (nbg > GB ? GB : nbg);
        if (nbg == 0) { tDone = t; break; }

        // ---- poll: all waves self-release on 192 wave-flags (3 lines) ----
        if (t > 0) {
            const unsigned target = (unsigned)t;
            long guard = 0;
            for (;;) {
                unsigned f0 = __hip_atomic_load(wflg + lane, __ATOMIC_RELAXED,
                                                __HIP_MEMORY_SCOPE_AGENT);
                unsigned f1 = __hip_atomic_load(wflg + 64 + lane, __ATOMIC_RELAXED,
                                                __HIP_MEMORY_SCOPE_AGENT);
                unsigned f2 = __hip_atomic_load(wflg + 128 + lane, __ATOMIC_RELAXED,
                                                __HIP_MEMORY_SCOPE_AGENT);
                bool ok = (f0 >= target) && (f1 >= target) && (f2 >= target);
                if (__all(ok)) break;
                if (++guard > gmax) break;
                __builtin_amdgcn_s_sleep(1);
            }
        }
        __asm__ volatile("" ::: "memory");

        // ---- ps-GEMM: A-fragments straight from the global h buffer ----
        {
            const unsigned long long* aB = (const unsigned long long*)hb[t & 1];
#pragma unroll
            for (int kb = 0; kb < 24; ++kb) {
                unsigned long long v0 = __hip_atomic_load(aB + kb * 128 + aoff,
                                                          __ATOMIC_RELAXED,
                                                          __HIP_MEMORY_SCOPE_AGENT);
                unsigned long long v1 = __hip_atomic_load(aB + kb * 128 + aoff + 1,
                                                          __ATOMIC_RELAXED,
                                                          __HIP_MEMORY_SCOPE_AGENT);
                short8 a;
                __builtin_memcpy(&a, &v0, 8);
                __builtin_memcpy((char*)&a + 8, &v1, 8);
                short8 b = __builtin_bit_cast(short8, *(const uint4*)(wsP + kb * 32));
                switch (kb & 3) {
                case 0: acc0 = __builtin_amdgcn_mfma_f32_16x16x32_bf16(a, b, acc0, 0, 0, 0); break;
                case 1: acc1 = __builtin_amdgcn_mfma_f32_16x16x32_bf16(a, b, acc1, 0, 0, 0); break;
                case 2: acc2 = __builtin_amdgcn_mfma_f32_16x16x32_bf16(a, b, acc2, 0, 0, 0); break;
                default: acc3 = __builtin_amdgcn_mfma_f32_16x16x32_bf16(a, b, acc3, 0, 0, 0); break;
                }
            }
        }
        {
            f4 s = (acc0 + acc1) + (acc2 + acc3);
            int r0 = (lane >> 4) * 4, col = lane & 15;
#pragma unroll
            for (int i = 0; i < 4; ++i) accT[wave][r0 + i][col] = s[i];
        }
        __syncthreads();   // b2: accT ready

        // ---- combine + publish + wave-autonomous release ----
        float y0 = 0, y1 = 0, y2 = 0, y3 = 0;
        size_t oiY = 0; bool doY = false;
        if (tid < 128) {
            int b = tid >> 3, j = tid & 7;
            float v0 = accT[(0 * 8 + j) >> 4][b][(0 * 8 + j) & 15];
            float v1 = accT[(1 * 8 + j) >> 4][b][(1 * 8 + j) & 15];
            float v2 = accT[(2 * 8 + j) >> 4][b][(2 * 8 + j) & 15];
            float v3 = accT[(3 * 8 + j) >> 4][b][(3 * 8 + j) & 15];
            float v4 = accT[(4 * 8 + j) >> 4][b][(4 * 8 + j) & 15];
            float v5 = accT[(5 * 8 + j) >> 4][b][(5 * 8 + j) & 15];
            float ii = sigm(v0 + B0);
            float ff = sigm(v1 + B1);
            float gg = tanh_(v2 + B2);
            float oo = sigm(v3 + B3);
            float hw = sigm(v4 + B4);
            float p5 = v5 + B5;
            float cn = ii * gg + ff * cReg;
            float outv = oo * tanh_(cn);
            outv = hw * outv + (1.0f - hw) * p5;
            bool act = t < lenb;
            if (act) cReg = cn;

            // gather the 4-lane subgroup's outv (f32) once; reuse for h and y
            int lane6 = tid & 63;
            int g0 = lane6 & ~3;
            float f0v = __shfl(outv, g0 + 0);
            float f1v = __shfl(outv, g0 + 1);
            float f2v = __shfl(outv, g0 + 2);
            float f3v = __shfl(outv, g0 + 3);
            if ((lane6 & 3) == 0) {
                if (act) {
                    unsigned long long vv = (unsigned long long)f2bf(f0v)
                        | ((unsigned long long)f2bf(f1v) << 16)
                        | ((unsigned long long)f2bf(f2v) << 32)
                        | ((unsigned long long)f2bf(f3v) << 48);
                    __hip_atomic_store(
                        (unsigned long long*)(hb[(t & 1) ^ 1] + w * 128 + b * 8 + j),
                        vv, __ATOMIC_RELAXED, __HIP_MEMORY_SCOPE_AGENT);
                }
                doY = true;
                y0 = act ? f0v : 0.0f; y1 = act ? f1v : 0.0f;
                y2 = act ? f2v : 0.0f; y3 = act ? f3v : 0.0f;
                oiY = ((size_t)(g * GB + b) * Tt + t) * Hh + n0 + j;
            }
            // wave-autonomous release: drain own h-store, set own wave-flag
            __asm__ volatile("s_waitcnt vmcnt(0)" ::: "memory");
            if (lane6 == 0)
                __hip_atomic_store(wflg + w * 2 + wave, (unsigned)(t + 1),
                                   __ATOMIC_RELAXED, __HIP_MEMORY_SCOPE_AGENT);
        }

        // ---- post-flag slack work: x_{t+1} -> LDS ----
        if (t + 1 < Tt) pfWrite();
        __syncthreads();   // b1: hA(x_{t+1}) ready

        // ---- x-GEMM for t+1 (rides the wait slack of the next poll) ----
        acc0 = f4{0, 0, 0, 0}; acc1 = f4{0, 0, 0, 0};
        acc2 = f4{0, 0, 0, 0}; acc3 = f4{0, 0, 0, 0};
        if (t + 1 < Tt) {
#pragma unroll
            for (int kb = 0; kb < 24; ++kb) {
                short8 a = __builtin_bit_cast(short8, *(const uint4*)(aP + kb * 32));
                short8 b = __builtin_bit_cast(short8, bPx[kb * 4]);
                switch (kb & 3) {
                case 0: acc0 = __builtin_amdgcn_mfma_f32_16x16x32_bf16(a, b, acc0, 0, 0, 0); break;
                case 1: acc1 = __builtin_amdgcn_mfma_f32_16x16x32_bf16(a, b, acc1, 0, 0, 0); break;
                case 2: acc2 = __builtin_amdgcn_mfma_f32_16x16x32_bf16(a, b, acc2, 0, 0, 0); break;
                default: acc3 = __builtin_amdgcn_mfma_f32_16x16x32_bf16(a, b, acc3, 0, 0, 0); break;
                }
            }
        }
        // ---- issue x_{t+2} prefetch (in flight for a full step) ----
        if (t + 2 < Tt) pfIssue(t + 2);
        __builtin_amdgcn_sched_barrier(0);

        // ---- y store LAST (16B float4 / 8B bf16x4; ack drains a chain later) ----
        if (doY) {
            if (isbf) {
                unsigned long long vv = (unsigned long long)f2bf(y0)
                    | ((unsigned long long)f2bf(y1) << 16)
                    | ((unsigned long long)f2bf(y2) << 32)
                    | ((unsigned long long)f2bf(y3) << 48);
                *(unsigned long long*)((ushort*)y + oiY) = vv;
            } else {
                *(f4*)((float*)y + oiY) = f4{y0, y1, y2, y3};
            }
        }
    }

    // ---- tail: group finished -> zero its remaining y cells ----
    if (tid < 128) {
        int b = tid >> 3, j = tid & 7;
        for (int t = tDone; t < Tt; ++t) {
            size_t oi = ((size_t)(g * GB + b) * Tt + t) * Hh + n0 + j;
            if (isbf) ((ushort*)y)[oi] = 0; else ((float*)y)[oi] = 0.0f;
        }
    }
}

extern "C" void kernel_launch(void* const* d_in, const int* in_sizes, int n_in,
                              void* d_out, int out_size, void* d_ws, size_t ws_size,
                              hipStream_t stream) {
    const void* inp = d_in[0];
    const void* Win = d_in[1];
    const void* bin = d_in[2];
    const void* Ws  = d_in[3];
    const void* bs  = d_in[4];
    const int*  len = (const int*)d_in[5];

    if (ws_size < WS_NEED) return;  // evidence: >=26.6 MB granted; need ~13.1 MB

    char* ws = (char*)d_ws;
    int* nbArr      = (int*)ws;
    unsigned* flags = (unsigned*)(ws + WS_NB);
    ushort* hbAll   = (ushort*)(ws + WS_HBOFF);
    ushort* wbf     = (ushort*)(ws + WS_WGT);

    hipMemsetAsync(d_ws, 0, WS_WGT, stream);   // nbArr/flags/h buffers = 0
    prep_nb<<<4, 256, 0, stream>>>(len, nbArr);
    conv_w<<<3168, 256, 0, stream>>>(Win, Ws, bs, wbf);
    lstm_main<<<NGRP * BPG, NTHREADS, 0, stream>>>(inp, bin, bs, len, d_out,
                                                   nbArr, flags, hbAll, wbf);
}